// Round 1
// baseline (56.073 us; speedup 1.0000x reference)
//
#include <hip/hip_runtime.h>
#include <hip/hip_bf16.h>
#include <stdint.h>

#define M_DIM 128
#define N_DIM 8192
#define K_DIM 8192
#define KP    4096      // packed int32 per weight row
#define NGRP  64
#define BN    128
#define BK    64

typedef __attribute__((ext_vector_type(8))) short bf16x8;
typedef __attribute__((ext_vector_type(4))) float f32x4;

__device__ __forceinline__ unsigned short f2bf(float f) {
  unsigned int u = __float_as_uint(f);
  return (unsigned short)((u + 0x7fffu + ((u >> 16) & 1u)) >> 16);
}

__global__ void xcast_kernel(const float* __restrict__ x, unsigned short* __restrict__ xb) {
  int idx = (blockIdx.x * blockDim.x + threadIdx.x) * 8;
  const float4* xp = (const float4*)(x + idx);
  float4 a = xp[0], b = xp[1];
  uint4 o;
  o.x = (unsigned)f2bf(a.x) | ((unsigned)f2bf(a.y) << 16);
  o.y = (unsigned)f2bf(a.z) | ((unsigned)f2bf(a.w) << 16);
  o.z = (unsigned)f2bf(b.x) | ((unsigned)f2bf(b.y) << 16);
  o.w = (unsigned)f2bf(b.z) | ((unsigned)f2bf(b.w) << 16);
  *(uint4*)(xb + idx) = o;
}

__global__ __launch_bounds__(256, 2)
void gemm_kernel(const unsigned short* __restrict__ xb,
                 const int* __restrict__ wq,
                 const float* __restrict__ scale,
                 const float* __restrict__ zpt,
                 float* __restrict__ partial,
                 int kchunk, int nsteps)
{
  // tiles: x 128xBK bf16, W 128xBK bf16; each row = 8 x 16B chunks, XOR-swizzled
  __shared__ uint4 xbuf[2][128 * 8];
  __shared__ uint4 wbuf[2][128 * 8];

  const int tid = threadIdx.x;
  const int l   = tid & 63;
  const int w   = tid >> 6;
  const int n0  = blockIdx.x * BN;
  const int ks  = blockIdx.y;
  const int k_base = ks * kchunk;

  f32x4 acc[4][4];
  #pragma unroll
  for (int i = 0; i < 4; ++i)
    #pragma unroll
    for (int j = 0; j < 4; ++j) {
      f32x4 z = {0.f, 0.f, 0.f, 0.f};
      acc[i][j] = z;
    }

  int4  wreg[4];
  float screg[4], zreg[4];

  // --- staging: x tile via global_load_lds (linear LDS dest, pre-swizzled global src)
  auto issue_x = [&](int t, int nb) {
    const int k0 = k_base + t * BK;
    #pragma unroll
    for (int i = 0; i < 4; ++i) {
      int rloc = i * 32 + w * 8 + (l >> 3);                      // LDS row 0..127
      const unsigned short* src = xb + (size_t)rloc * K_DIM + k0
                                  + (((l & 7) ^ ((l >> 3) & 7)) * 8);
      uint4* dst = &xbuf[nb][(i * 32 + w * 8) * 8];              // wave-uniform base
      __builtin_amdgcn_global_load_lds(
          (__attribute__((address_space(1))) void*)(void*)src,
          (__attribute__((address_space(3))) void*)(void*)dst, 16, 0, 0);
    }
  };

  // --- staging: W packed int32 -> regs (prefetch)
  auto load_w = [&](int t) {
    const int k0 = k_base + t * BK;
    const int g  = k0 >> 7;                  // one scale group per BK=64 step
    const int kp0 = (k0 >> 1) + (tid & 7) * 4;
    #pragma unroll
    for (int i = 0; i < 4; ++i) {
      int row = n0 + i * 32 + (tid >> 3);
      wreg[i]  = *(const int4*)(wq + (size_t)row * KP + kp0);
      screg[i] = scale[row * NGRP + g];
      zreg[i]  = zpt[row * NGRP + g];
    }
  };

  // --- dequant + swizzled ds_write
  auto write_w = [&](int nb) {
    #pragma unroll
    for (int i = 0; i < 4; ++i) {
      int r = i * 32 + (tid >> 3);
      int q = tid & 7;
      float sc = screg[i];
      float nz = -zreg[i] * sc;
      int vals[4] = {wreg[i].x, wreg[i].y, wreg[i].z, wreg[i].w};
      unsigned int words[4];
      #pragma unroll
      for (int j = 0; j < 4; ++j) {
        int hi = (vals[j] << 24) >> 28;      // bits 7:4 sign-extended (k = 2j)
        int lo = (vals[j] << 28) >> 28;      // bits 3:0 sign-extended (k = 2j+1)
        float fh = fmaf((float)hi, sc, nz);
        float fl = fmaf((float)lo, sc, nz);
        words[j] = (unsigned)f2bf(fh) | ((unsigned)f2bf(fl) << 16);
      }
      uint4 o; o.x = words[0]; o.y = words[1]; o.z = words[2]; o.w = words[3];
      wbuf[nb][r * 8 + (q ^ (r & 7))] = o;
    }
  };

  const int wr = w >> 1, wc = w & 1;

  auto compute = [&](int cb) {
    #pragma unroll
    for (int kk = 0; kk < 2; ++kk) {
      uint4 av[4], bv[4];
      const int q = kk * 4 + (l >> 4);
      #pragma unroll
      for (int mi = 0; mi < 4; ++mi) {
        int r = wr * 64 + mi * 16 + (l & 15);
        av[mi] = xbuf[cb][r * 8 + (q ^ (r & 7))];
      }
      #pragma unroll
      for (int ni = 0; ni < 4; ++ni) {
        int r = wc * 64 + ni * 16 + (l & 15);
        bv[ni] = wbuf[cb][r * 8 + (q ^ (r & 7))];
      }
      #pragma unroll
      for (int mi = 0; mi < 4; ++mi)
        #pragma unroll
        for (int ni = 0; ni < 4; ++ni)
          acc[mi][ni] = __builtin_amdgcn_mfma_f32_16x16x32_bf16(
              __builtin_bit_cast(bf16x8, av[mi]),
              __builtin_bit_cast(bf16x8, bv[ni]),
              acc[mi][ni], 0, 0, 0);
    }
  };

  // prologue
  issue_x(0, 0);
  load_w(0);
  write_w(0);
  __syncthreads();

  for (int t = 0; t < nsteps; ++t) {
    const int cb = t & 1, nb = (t + 1) & 1;
    if (t + 1 < nsteps) { issue_x(t + 1, nb); load_w(t + 1); }
    compute(cb);
    if (t + 1 < nsteps) { write_w(nb); __syncthreads(); }
  }

  // epilogue: write fp32 partial
  float* pout = partial + (size_t)ks * (M_DIM * N_DIM);
  #pragma unroll
  for (int mi = 0; mi < 4; ++mi)
    #pragma unroll
    for (int ni = 0; ni < 4; ++ni) {
      int row = wr * 64 + mi * 16 + ((l >> 4) * 4);
      int col = n0 + wc * 64 + ni * 16 + (l & 15);
      f32x4 v = acc[mi][ni];
      #pragma unroll
      for (int j = 0; j < 4; ++j)
        pout[(size_t)(row + j) * N_DIM + col] = v[j];
    }
}

__global__ void reduce_kernel(const float* __restrict__ part,
                              const float* __restrict__ bias,
                              float* __restrict__ out, int ksplit) {
  int idx = (blockIdx.x * blockDim.x + threadIdx.x) * 4;
  float4 s = *(const float4*)(part + idx);
  for (int k = 1; k < ksplit; ++k) {
    float4 p = *(const float4*)(part + (size_t)k * (M_DIM * N_DIM) + idx);
    s.x += p.x; s.y += p.y; s.z += p.z; s.w += p.w;
  }
  float4 b = *(const float4*)(bias + (idx & (N_DIM - 1)));
  s.x += b.x; s.y += b.y; s.z += b.z; s.w += b.w;
  *(float4*)(out + idx) = s;
}

extern "C" void kernel_launch(void* const* d_in, const int* in_sizes, int n_in,
                              void* d_out, int out_size, void* d_ws, size_t ws_size,
                              hipStream_t stream) {
  const float* x     = (const float*)d_in[0];
  const int*   wq    = (const int*)d_in[1];
  const float* scale = (const float*)d_in[2];
  const float* zpt   = (const float*)d_in[3];
  const float* bias  = (const float*)d_in[4];
  float* out = (float*)d_out;

  unsigned short* xb = (unsigned short*)d_ws;
  const size_t xbytes = (size_t)M_DIM * K_DIM * 2;        // 2 MiB
  float* partial = (float*)((char*)d_ws + xbytes);
  const size_t per_split = (size_t)M_DIM * N_DIM * 4;     // 4 MiB

  int ksplit = 8;
  while (ksplit > 1 && xbytes + (size_t)ksplit * per_split > ws_size) ksplit >>= 1;
  const int kchunk = K_DIM / ksplit;
  const int nsteps = kchunk / BK;

  xcast_kernel<<<(M_DIM * K_DIM) / (256 * 8), 256, 0, stream>>>(x, xb);
  gemm_kernel<<<dim3(N_DIM / BN, ksplit), 256, 0, stream>>>(
      xb, wq, scale, zpt, partial, kchunk, nsteps);
  reduce_kernel<<<(M_DIM * N_DIM) / (256 * 4), 256, 0, stream>>>(
      partial, bias, out, ksplit);
}